// Round 14
// baseline (317.024 us; speedup 1.0000x reference)
//
#include <hip/hip_runtime.h>

#define N_F     64
#define N_REL   32
#define BLOCK   256
#define SCAN_TILE 2048

typedef __attribute__((ext_vector_type(8))) short bf16x8;   // 8 bf16 = 4 VGPRs
typedef __attribute__((ext_vector_type(4))) float f32x4;

__device__ __forceinline__ unsigned short f2bf(float f) {
    unsigned u = __float_as_uint(f);
    u += 0x7FFF + ((u >> 16) & 1);          // RNE
    return (unsigned short)(u >> 16);
}

// ---------------------------------------------------------------------------
// K-pre: region-branched fusion of cast+self | relw | hist.
// Cast blocks (64 nodes each) also compute out = x @ selfW + bias (k_recv
// later adds agg/deg via RMW). Hist blocks persist per-rel histograms (plain
// stores; cnt1 = row sums computed in k_scan_sums).
// ---------------------------------------------------------------------------
__global__ void __launch_bounds__(BLOCK) k_pre(const float* __restrict__ nf,
                                               const int* __restrict__ rel,
                                               const int* __restrict__ rcv,
                                               const float* __restrict__ basis,
                                               const float* __restrict__ coeff,
                                               const float* __restrict__ selfw,
                                               const float* __restrict__ bias,
                                               unsigned short* __restrict__ xbf,
                                               unsigned short* __restrict__ Wsh,
                                               float* __restrict__ out,
                                               int* __restrict__ S,    // [0,N): cnt2, [N,..): bh
                                               int E, int N, int nbh,
                                               int nbCast, int nbRelw) {
    const int bid = blockIdx.x;
    if (bid < nbCast) {
        const int nb0 = bid * 64;
        const int len = min(64, N - nb0);
        // cast: len nodes = len*16 float4
        const float4* src = (const float4*)(nf + (size_t)nb0 * N_F);
        ushort4* dst = (ushort4*)(xbf + (size_t)nb0 * N_F);
        for (int i = threadIdx.x; i < len * 16; i += BLOCK) {
            float4 v = src[i];
            ushort4 o;
            o.x = f2bf(v.x); o.y = f2bf(v.y); o.z = f2bf(v.z); o.w = f2bf(v.w);
            dst[i] = o;
        }
        // self-loop: out = x @ selfW + bias  (lane = feature, 4 waves x nodes)
        const int lane = threadIdx.x & 63;
        const int wave = threadIdx.x >> 6;
        float swcol[N_F];
#pragma unroll
        for (int i = 0; i < N_F; ++i) swcol[i] = selfw[i * N_F + lane];
        const float bv = bias[lane];
        for (int nl = wave; nl < len; nl += 4) {
            const float4* xr = (const float4*)(nf + (size_t)(nb0 + nl) * N_F);
            float s0 = 0.f, s1 = 0.f, s2 = 0.f, s3 = 0.f;
#pragma unroll
            for (int q = 0; q < 16; ++q) {
                float4 xv = xr[q];                            // broadcast
                s0 = __builtin_fmaf(xv.x, swcol[4 * q + 0], s0);
                s1 = __builtin_fmaf(xv.y, swcol[4 * q + 1], s1);
                s2 = __builtin_fmaf(xv.z, swcol[4 * q + 2], s2);
                s3 = __builtin_fmaf(xv.w, swcol[4 * q + 3], s3);
            }
            out[(size_t)(nb0 + nl) * N_F + lane] = (s0 + s1) + (s2 + s3) + bv;
        }
    } else if (bid < nbCast + nbRelw) {
        int idx = (bid - nbCast) * BLOCK + threadIdx.x;
        if (idx < N_REL * N_F * N_F) {
            int r  = idx >> 12;
            int io = idx & 4095;          // k*64 + n
            int k  = io >> 6;
            int n  = io & 63;
            float acc = 0.f;
#pragma unroll
            for (int b = 0; b < 30; ++b)
                acc += coeff[r * 30 + b] * basis[b * (N_F * N_F) + io];
            int ks = k >> 5, kk = k & 31;
            int nt = n >> 4, nl = n & 15;
            int lane = ((kk >> 3) << 4) | nl;
            int j    = kk & 7;
            Wsh[((((r * 2 + ks) * 4 + nt) * 64 + lane) << 3) + j] = f2bf(acc);
        }
    } else {
        __shared__ int h[N_REL];
        if (threadIdx.x < N_REL) h[threadIdx.x] = 0;
        __syncthreads();
        const int bidh = bid - nbCast - nbRelw;
        int e = bidh * BLOCK + threadIdx.x;
        if (e < E) {
            atomicAdd(&h[rel[e]], 1);
            atomicAdd(&S[rcv[e]], 1);          // cnt2 (scattered, benign)
        }
        __syncthreads();
        if (threadIdx.x < N_REL)
            S[N + threadIdx.x * nbh + bidh] = h[threadIdx.x];   // bh (plain store)
    }
}

// ---------------------------------------------------------------------------
// Scan stage 1 over S = [cnt2 | bh] + region-branched cnt1 row-sums
// ---------------------------------------------------------------------------
__global__ void k_scan_sums(const int* __restrict__ cur, int* __restrict__ part,
                            int* __restrict__ cnt1,
                            int nbins, int npart, int N, int nbh) {
    __shared__ int red[BLOCK];
    const int bid = blockIdx.x;
    if (bid >= npart) {
        const int r = bid - npart;
        const int* row = cur + N + (size_t)r * nbh;
        int s = 0;
        for (int i = threadIdx.x; i < nbh; i += BLOCK) s += row[i];
        red[threadIdx.x] = s;
        __syncthreads();
        for (int off = BLOCK / 2; off > 0; off >>= 1) {
            if (threadIdx.x < off) red[threadIdx.x] += red[threadIdx.x + off];
            __syncthreads();
        }
        if (threadIdx.x == 0) cnt1[r] = red[0];
        return;
    }
    int base = bid * SCAN_TILE;
    int s = 0;
    for (int i = threadIdx.x; i < SCAN_TILE; i += BLOCK) {
        int idx = base + i;
        s += (idx < nbins) ? cur[idx] : 0;
    }
    red[threadIdx.x] = s;
    __syncthreads();
    for (int off = BLOCK / 2; off > 0; off >>= 1) {
        if (threadIdx.x < off) red[threadIdx.x] += red[threadIdx.x + off];
        __syncthreads();
    }
    if (threadIdx.x == 0) part[bid] = red[0];
}

// ---------------------------------------------------------------------------
// Single-block middle: scan of tile sums + rel-bin bases + pad-slot init.
// ---------------------------------------------------------------------------
__global__ void k_scan_mid(const int* __restrict__ cnt1, int* __restrict__ base1,
                           int* __restrict__ ub1, int* __restrict__ part,
                           int* __restrict__ esrc, int* __restrict__ perm,
                           int npart, int Ppad) {
    __shared__ int buf[BLOCK];
    __shared__ int scnt[N_REL];
    __shared__ int sbase[N_REL + 1];
    __shared__ int stotal;
    const int tid = threadIdx.x;

    if (tid < N_REL) scnt[tid] = cnt1[tid];

    int v = (tid < npart) ? part[tid] : 0;
    buf[tid] = v;
    __syncthreads();
    for (int off = 1; off < BLOCK; off <<= 1) {
        int t = (tid >= off) ? buf[tid - off] : 0;
        __syncthreads();
        buf[tid] += t;
        __syncthreads();
    }
    if (tid < npart) part[tid] = buf[tid] - v;

    if (tid == 0) {
        int acc = 0, uacc = 0;
        for (int r = 0; r < N_REL; ++r) {
            base1[r] = acc;
            sbase[r] = acc;
            ub1[r]   = uacc;
            acc  += (scnt[r] + 15) & ~15;
            uacc += scnt[r];
        }
        base1[N_REL] = Ppad;
        sbase[N_REL] = Ppad;
        ub1[N_REL]   = uacc;
        stotal = acc;
    }
    __syncthreads();

    for (int i = tid; i < N_REL * 16; i += BLOCK) {
        int r = i >> 4, o = i & 15;
        int c  = scnt[r];
        int p0 = sbase[r] + c;
        int p1 = sbase[r] + ((c + 15) & ~15);
        int p  = p0 + o;
        if (p < p1) { perm[p] = -1; esrc[p] = 0; }
    }
    for (int p = stotal + tid; p < Ppad; p += BLOCK) {
        perm[p] = -1; esrc[p] = 0;
    }
}

// ---------------------------------------------------------------------------
// Scan stage 3 over S (+ fused tile->relation table)
// ---------------------------------------------------------------------------
__global__ void k_scan_apply_tile(int* __restrict__ cur, const int* __restrict__ part,
                                  const int* __restrict__ base1,
                                  unsigned char* __restrict__ trel,
                                  int nbins, int npart, int T) {
    if ((int)blockIdx.x >= npart) {
        int t = (blockIdx.x - npart) * BLOCK + threadIdx.x;
        if (t < T) {
            int p = t << 4;
            int r = 0;
#pragma unroll
            for (int i = 1; i < N_REL; ++i) r += (p >= base1[i]);
            trel[t] = (unsigned char)r;
        }
        return;
    }
    __shared__ int buf[BLOCK];
    int base_t = blockIdx.x * SCAN_TILE + threadIdx.x * 8;
    int loc[8];
    int s = 0;
#pragma unroll
    for (int j = 0; j < 8; ++j) {
        int idx = base_t + j;
        int v = (idx < nbins) ? cur[idx] : 0;
        loc[j] = s;
        s += v;
    }
    buf[threadIdx.x] = s;
    __syncthreads();
    for (int off = 1; off < BLOCK; off <<= 1) {
        int t = (threadIdx.x >= off) ? buf[threadIdx.x - off] : 0;
        __syncthreads();
        buf[threadIdx.x] += t;
        __syncthreads();
    }
    int excl = buf[threadIdx.x] - s + part[blockIdx.x];
#pragma unroll
    for (int j = 0; j < 8; ++j) {
        int idx = base_t + j;
        if (idx < nbins) cur[idx] = loc[j] + excl;
    }
}

// ---------------------------------------------------------------------------
// Scatter: pos1 via per-block scanned base + LDS rank (no global atomics);
// pos2 via mild scattered cur2 atomic. One barrier.
// ---------------------------------------------------------------------------
__global__ void __launch_bounds__(BLOCK) k_scatter1(const int* __restrict__ snd,
                                                    const int* __restrict__ rcv,
                                                    const int* __restrict__ rel,
                                                    int* S,
                                                    const int* __restrict__ base1,
                                                    const int* __restrict__ ub1,
                                                    int* __restrict__ esrc,
                                                    int* __restrict__ perm,
                                                    int E, int N, int nbh) {
    __shared__ int h[N_REL], bhb[N_REL];
    const int b = blockIdx.x;
    if (threadIdx.x < N_REL) {
        int g = S[N + threadIdx.x * nbh + b];              // includes +E offset
        bhb[threadIdx.x] = base1[threadIdx.x] + (g - E - ub1[threadIdx.x]);
        h[threadIdx.x] = 0;
    }
    __syncthreads();
    int e = b * BLOCK + threadIdx.x;
    if (e < E) {
        int r = rel[e];
        int rank = atomicAdd(&h[r], 1);
        int pos1 = bhb[r] + rank;
        int pos2 = atomicAdd(&S[rcv[e]], 1);
        esrc[pos1] = snd[e];
        perm[pos1] = pos2;
    }
}

// ---------------------------------------------------------------------------
// Phase A: per-tile GEMM -> bf16 edge rows at receiver-sorted positions.
// 1-deep prefetch of next tile's esrc/perm. No barriers/atomics.
// ---------------------------------------------------------------------------
__global__ void __launch_bounds__(BLOCK) k_gemm(const unsigned short* __restrict__ xbf,
                                                const int* __restrict__ esrc,
                                                const int* __restrict__ perm,
                                                const unsigned char* __restrict__ trel,
                                                const unsigned short* __restrict__ Wsh,
                                                unsigned short* __restrict__ eoutb,
                                                int T, int tpw, int dumprow) {
    __shared__ float ts[4][16 * 68];        // per-wave 16x64 transpose, stride 68
    const int tid  = threadIdx.x;
    const int lane = tid & 63;
    const int wave = tid >> 6;
    float* tb = ts[wave];

    const int gw = blockIdx.x * 4 + wave;
    const int t0 = gw * tpw;
    const int t1 = min(t0 + tpw, T);
    if (t0 >= T) return;

    const int row = lane & 15;
    const int kg  = lane >> 4;
    const int rr  = lane >> 2;      // store-phase row
    const int ch  = lane & 3;       // store-phase 16-col chunk

    int curR = -1;
    bf16x8 wf[2][4];

    int s_cur  = esrc[(t0 << 4) + row];
    int pm_cur = perm[(t0 << 4) + row];

    for (int t = t0; t < t1; ++t) {
        int s_nxt = 0, pm_nxt = -1;
        if (t + 1 < t1) {
            s_nxt  = esrc[((t + 1) << 4) + row];
            pm_nxt = perm[((t + 1) << 4) + row];
        }

        const int r = trel[t];
        if (r != curR) {
            curR = r;
#pragma unroll
            for (int ks = 0; ks < 2; ++ks)
#pragma unroll
                for (int nt = 0; nt < 4; ++nt)
                    wf[ks][nt] = *(const bf16x8*)(Wsh + ((((r * 2 + ks) * 4 + nt) * 64 + lane) << 3));
        }

        const size_t xb = ((size_t)s_cur << 6) + (kg << 3);
        bf16x8 a0 = *(const bf16x8*)(xbf + xb);
        bf16x8 a1 = *(const bf16x8*)(xbf + xb + 32);

        f32x4 acc[4];
#pragma unroll
        for (int nt = 0; nt < 4; ++nt) {
            acc[nt] = (f32x4){0.f, 0.f, 0.f, 0.f};
            acc[nt] = __builtin_amdgcn_mfma_f32_16x16x32_bf16(a0, wf[0][nt], acc[nt], 0, 0, 0);
            acc[nt] = __builtin_amdgcn_mfma_f32_16x16x32_bf16(a1, wf[1][nt], acc[nt], 0, 0, 0);
        }

        // C-layout (col=lane&15, row=kg*4+reg) -> LDS row-major
#pragma unroll
        for (int nt = 0; nt < 4; ++nt)
#pragma unroll
            for (int reg = 0; reg < 4; ++reg)
                tb[(kg * 4 + reg) * 68 + nt * 16 + (lane & 15)] = acc[nt][reg];

        asm volatile("s_waitcnt lgkmcnt(0)" ::: "memory");   // wave-local RAW

        int pmr = __shfl(pm_cur, rr);         // dest row of store-phase row
        pmr = (pmr < 0) ? dumprow : pmr;      // pad rows -> dump

        const float* src = tb + rr * 68 + ch * 16;
        unsigned pk[8];
#pragma unroll
        for (int q = 0; q < 4; ++q) {
            float4 v = *(const float4*)(src + q * 4);
            pk[2 * q]     = (unsigned)f2bf(v.x) | ((unsigned)f2bf(v.y) << 16);
            pk[2 * q + 1] = (unsigned)f2bf(v.z) | ((unsigned)f2bf(v.w) << 16);
        }
        unsigned short* dst = eoutb + (size_t)pmr * 64 + ch * 16;
        uint4 v0; v0.x = pk[0]; v0.y = pk[1]; v0.z = pk[2]; v0.w = pk[3];
        uint4 v1; v1.x = pk[4]; v1.y = pk[5]; v1.z = pk[6]; v1.w = pk[7];
        *(uint4*)dst       = v0;
        *(uint4*)(dst + 8) = v1;

        s_cur = s_nxt; pm_cur = pm_nxt;
    }
}

// ---------------------------------------------------------------------------
// Phase B: 8-lane group per node (sub = lane>>3, c = lane&7). Each lane
// accumulates its 8 features (uint4 = 16 B/lane = 1 KB/wave-load). No
// cross-lane reduction at all. out += agg/deg (self+bias already in out
// from k_pre). Unroll-4 for loads in flight.
// ---------------------------------------------------------------------------
__global__ void __launch_bounds__(BLOCK) k_recv(const unsigned short* __restrict__ eoutb,
                                                const int* __restrict__ cur2,
                                                float* __restrict__ out,
                                                int N) {
    const int lane = threadIdx.x & 63;
    const int wave = threadIdx.x >> 6;
    const int nb   = (blockIdx.x * 4 + wave) * 8;     // 8 nodes per wave
    if (nb >= N) return;

    const int sub = lane >> 3;      // node within group of 8
    const int c   = lane & 7;       // feature oct (feats 8c..8c+7)

    int bidx = nb - 1 + lane;
    int bnd  = 0;
    if (lane <= 8 && bidx >= 0 && bidx < N) bnd = cur2[bidx];
    int st = __shfl(bnd, sub);
    int en = __shfl(bnd, sub + 1);
    const int n = nb + sub;
    if (n >= N) { st = 0; en = 0; }

    float a[8];
#pragma unroll
    for (int i = 0; i < 8; ++i) a[i] = 0.f;

    const uint4* ep = (const uint4*)eoutb;            // 8 uint4 per row
    int j = st;
    for (; j + 4 <= en; j += 4) {
        uint4 u0 = ep[(size_t)(j + 0) * 8 + c];
        uint4 u1 = ep[(size_t)(j + 1) * 8 + c];
        uint4 u2 = ep[(size_t)(j + 2) * 8 + c];
        uint4 u3 = ep[(size_t)(j + 3) * 8 + c];
        a[0] += (__uint_as_float(u0.x << 16) + __uint_as_float(u1.x << 16)) +
                (__uint_as_float(u2.x << 16) + __uint_as_float(u3.x << 16));
        a[1] += (__uint_as_float(u0.x & 0xFFFF0000u) + __uint_as_float(u1.x & 0xFFFF0000u)) +
                (__uint_as_float(u2.x & 0xFFFF0000u) + __uint_as_float(u3.x & 0xFFFF0000u));
        a[2] += (__uint_as_float(u0.y << 16) + __uint_as_float(u1.y << 16)) +
                (__uint_as_float(u2.y << 16) + __uint_as_float(u3.y << 16));
        a[3] += (__uint_as_float(u0.y & 0xFFFF0000u) + __uint_as_float(u1.y & 0xFFFF0000u)) +
                (__uint_as_float(u2.y & 0xFFFF0000u) + __uint_as_float(u3.y & 0xFFFF0000u));
        a[4] += (__uint_as_float(u0.z << 16) + __uint_as_float(u1.z << 16)) +
                (__uint_as_float(u2.z << 16) + __uint_as_float(u3.z << 16));
        a[5] += (__uint_as_float(u0.z & 0xFFFF0000u) + __uint_as_float(u1.z & 0xFFFF0000u)) +
                (__uint_as_float(u2.z & 0xFFFF0000u) + __uint_as_float(u3.z & 0xFFFF0000u));
        a[6] += (__uint_as_float(u0.w << 16) + __uint_as_float(u1.w << 16)) +
                (__uint_as_float(u2.w << 16) + __uint_as_float(u3.w << 16));
        a[7] += (__uint_as_float(u0.w & 0xFFFF0000u) + __uint_as_float(u1.w & 0xFFFF0000u)) +
                (__uint_as_float(u2.w & 0xFFFF0000u) + __uint_as_float(u3.w & 0xFFFF0000u));
    }
    for (; j < en; ++j) {
        uint4 u0 = ep[(size_t)j * 8 + c];
        a[0] += __uint_as_float(u0.x << 16);
        a[1] += __uint_as_float(u0.x & 0xFFFF0000u);
        a[2] += __uint_as_float(u0.y << 16);
        a[3] += __uint_as_float(u0.y & 0xFFFF0000u);
        a[4] += __uint_as_float(u0.z << 16);
        a[5] += __uint_as_float(u0.z & 0xFFFF0000u);
        a[6] += __uint_as_float(u0.w << 16);
        a[7] += __uint_as_float(u0.w & 0xFFFF0000u);
    }

    if (n < N) {
        float dg  = (float)(en - st);
        float inv = 1.f / (dg < 1.f ? 1.f : dg);
        float* op = out + (size_t)n * N_F + c * 8;
        float4 p0 = *(const float4*)op;
        float4 p1 = *(const float4*)(op + 4);
        p0.x += a[0] * inv; p0.y += a[1] * inv; p0.z += a[2] * inv; p0.w += a[3] * inv;
        p1.x += a[4] * inv; p1.y += a[5] * inv; p1.z += a[6] * inv; p1.w += a[7] * inv;
        *(float4*)op       = p0;
        *(float4*)(op + 4) = p1;
    }
}

// ---------------------------------------------------------------------------
extern "C" void kernel_launch(void* const* d_in, const int* in_sizes, int n_in,
                              void* d_out, int out_size, void* d_ws, size_t ws_size,
                              hipStream_t stream) {
    const float* nf    = (const float*)d_in[0];
    const int*   snd   = (const int*)  d_in[1];
    const int*   rcv   = (const int*)  d_in[2];
    const int*   rel   = (const int*)  d_in[3];
    const float* basis = (const float*)d_in[4];
    const float* coeff = (const float*)d_in[5];
    const float* selfw = (const float*)d_in[6];
    const float* bias  = (const float*)d_in[7];
    float*       out   = (float*)d_out;

    const int N = in_sizes[0] / N_F;                  // 100000
    const int E = in_sizes[1];                        // 1000000
    const int Ppad = (E + N_REL * 15 + 15) & ~15;     // padded rel-sorted length
    const int T    = Ppad >> 4;                       // total 16-edge tiles

    const int NB_CAST = (N + 63) / 64;                // 64 nodes per cast+self block
    const int NB_RELW = (N_REL * N_F * N_F + BLOCK - 1) / BLOCK;
    const int NB_HIST = (E + BLOCK - 1) / BLOCK;      // == nbh
    const int nbh     = NB_HIST;

    const int SCAN_N = N + N_REL * nbh;               // combined scan length
    const int NPART  = (SCAN_N + SCAN_TILE - 1) / SCAN_TILE;   // <= 256

    // ws layout
    unsigned short* eoutb = (unsigned short*)d_ws;                    // Ppad*64 bf16
    unsigned short* Wsh   = eoutb + (size_t)Ppad * N_F;               // 131072
    unsigned short* xbf   = Wsh + (size_t)N_REL * N_F * N_F;          // N*64
    int* base1 = (int*)(xbf + (size_t)N * N_F);                       // 64
    int* ub1   = base1 + 64;                                          // 64
    int* cnt1  = ub1 + 64;                                            // 32
    int* part  = cnt1 + 32;                                           // 256
    int* S     = part + 256;                                          // SCAN_N (memset)
    int* esrc  = S + SCAN_N;                                          // Ppad
    int* perm  = esrc + Ppad;                                         // Ppad
    unsigned char* trel = (unsigned char*)(perm + Ppad);              // T

    hipMemsetAsync(S, 0, (size_t)SCAN_N * sizeof(int), stream);

    k_pre<<<NB_CAST + NB_RELW + NB_HIST, BLOCK, 0, stream>>>(
        nf, rel, rcv, basis, coeff, selfw, bias, xbf, Wsh, out, S,
        E, N, nbh, NB_CAST, NB_RELW);

    k_scan_sums<<<NPART + N_REL, BLOCK, 0, stream>>>(S, part, cnt1, SCAN_N, NPART, N, nbh);
    k_scan_mid <<<1, BLOCK, 0, stream>>>(cnt1, base1, ub1, part, esrc, perm, NPART, Ppad);

    const int NB_TREL = (T + BLOCK - 1) / BLOCK;
    k_scan_apply_tile<<<NPART + NB_TREL, BLOCK, 0, stream>>>(S, part, base1, trel,
                                                             SCAN_N, NPART, T);

    k_scatter1<<<nbh, BLOCK, 0, stream>>>(snd, rcv, rel, S, base1, ub1, esrc, perm,
                                          E, N, nbh);

    const int GEMM_BLOCKS = 2048;                      // 8192 waves
    const int tpw = (T + GEMM_BLOCKS * 4 - 1) / (GEMM_BLOCKS * 4);
    k_gemm<<<GEMM_BLOCKS, BLOCK, 0, stream>>>(xbf, esrc, perm, trel, Wsh, eoutb, T, tpw, E);

    const int RECV_BLOCKS = (N + 31) / 32;             // 8 nodes/wave, 4 waves/block
    k_recv<<<RECV_BLOCKS, BLOCK, 0, stream>>>(eoutb, S, out, N);
}